// Round 1
// baseline (2740.112 us; speedup 1.0000x reference)
//
#include <hip/hip_runtime.h>
#include <math.h>

#define NGENES 2000
#define NCELLS 50000
#define NPHENO 64
#define NTOT   52064
#define NEDGE  1200000
#define D      128
#define SLOPE  0.2f
#define ENC_NEGINF 0x007FFFFFu   // ford(-inf)

// output layout (flat, return order)
#define O_ZSEN 6664192LL                  // NTOT*D
#define O_ZCTX 13064192LL                 // + NCELLS*D
#define O_G    16264192LL                 // + NCELLS*64
#define O_ZPH  16314192LL                 // + NCELLS

__device__ __forceinline__ float celu_f(float x){ return x > 0.f ? x : expm1f(x); }
__device__ __forceinline__ unsigned ford(float f){
    unsigned u = __float_as_uint(f);
    return (u & 0x80000000u) ? ~u : (u | 0x80000000u);
}
__device__ __forceinline__ float funord(unsigned u){
    return __uint_as_float((u & 0x80000000u) ? (u & 0x7fffffffu) : ~u);
}
__device__ __forceinline__ float wave_sum(float v){
    #pragma unroll
    for (int off = 32; off; off >>= 1) v += __shfl_xor(v, off);
    return v;
}

// ---------------- dense row-GEMM: Y[r] = act(X[r] @ W + b), W in LDS ----------------
// blockDim 256 = 4 waves, each wave owns rows [wid*16, wid*16+16)
template<int NCOLS, int ACT, bool AVEC>
__launch_bounds__(256)
__global__ void k_rowgemm(const float* __restrict__ X, const float* __restrict__ W,
                          const float* __restrict__ bias, float* __restrict__ Y,
                          const float* __restrict__ avs, const float* __restrict__ avd,
                          float* __restrict__ as_out, float* __restrict__ ad_out,
                          int nrows)
{
    __shared__ float Wl[D*NCOLS];
    int tid = threadIdx.x;
    for (int k = tid; k < D*NCOLS; k += 256) Wl[k] = W[k];
    __syncthreads();
    const int lane = tid & 63, wave = tid >> 6;
    const int wid = blockIdx.x * 4 + wave;
    float b0 = 0.f, b1 = 0.f;
    if (bias) { b0 = bias[lane]; if (NCOLS == 128) b1 = bias[64 + lane]; }
    float s0=0.f, s1=0.f, dd0=0.f, dd1=0.f;
    if (AVEC) { s0 = avs[lane]; s1 = avs[64+lane]; dd0 = avd[lane]; dd1 = avd[64+lane]; }
    int r0 = wid * 16;
    int r1 = r0 + 16; if (r1 > nrows) r1 = nrows;
    for (int r = r0; r < r1; ++r) {
        float x0 = X[(long)r*D + lane];
        float x1 = X[(long)r*D + 64 + lane];
        float a0 = b0, a1 = b1;
        #pragma unroll
        for (int k = 0; k < 64; ++k) {
            float xk = __shfl(x0, k);
            a0 = fmaf(xk, Wl[k*NCOLS + lane], a0);
            if (NCOLS == 128) a1 = fmaf(xk, Wl[k*NCOLS + 64 + lane], a1);
        }
        #pragma unroll
        for (int k = 0; k < 64; ++k) {
            float xk = __shfl(x1, k);
            a0 = fmaf(xk, Wl[(64+k)*NCOLS + lane], a0);
            if (NCOLS == 128) a1 = fmaf(xk, Wl[(64+k)*NCOLS + 64 + lane], a1);
        }
        float o0 = a0, o1 = a1;
        if (ACT == 1) { o0 = fmaxf(o0, 0.f); o1 = fmaxf(o1, 0.f); }
        if (ACT == 2) { o0 = celu_f(o0); o1 = celu_f(o1); }
        Y[(long)r*NCOLS + lane] = o0;
        if (NCOLS == 128) Y[(long)r*NCOLS + 64 + lane] = o1;
        if (AVEC) {
            float ps = a0*s0 + a1*s1;
            float pd = a0*dd0 + a1*dd1;
            ps = wave_sum(ps); pd = wave_sum(pd);
            if (lane == 0) { as_out[r] = ps; ad_out[r] = pd; }
        }
    }
}

// ---------------- phenotype MLP ----------------
__global__ void k_pheno(const float* __restrict__ praw, const float* __restrict__ W1,
                        const float* __restrict__ b1, const float* __restrict__ W2,
                        const float* __restrict__ b2, float* __restrict__ zout,
                        float* __restrict__ xA)
{
    __shared__ float z1[D];
    int i = blockIdx.x, j = threadIdx.x;
    float p = praw[i];
    z1[j] = celu_f(fmaf(p, W1[j], b1[j]));
    __syncthreads();
    float acc = b2[j];
    for (int k = 0; k < D; ++k) acc = fmaf(z1[k], W2[k*D + j], acc);
    float z = celu_f(acc);
    zout[i*D + j] = z;
    xA[(long)(NGENES + NCELLS + i)*D + j] = z;
}

// ---------------- GAT edge passes ----------------
__global__ void k_init_layer(float* __restrict__ xC, unsigned* __restrict__ emax,
                             float* __restrict__ den)
{
    long t = (long)blockIdx.x*blockDim.x + threadIdx.x;
    if (t < (long)NTOT*D) xC[t] = 0.f;
    if (t < NTOT) { emax[t] = ENC_NEGINF; den[t] = 0.f; }
}

__global__ void k_edge1(const int* __restrict__ ei, const float* __restrict__ as_,
                        const float* __restrict__ ad_, float* __restrict__ eed,
                        unsigned* __restrict__ emax)
{
    int e = blockIdx.x*blockDim.x + threadIdx.x;
    if (e >= NEDGE) return;
    int s = ei[e], d = ei[NEDGE + e];
    float v = as_[s] + ad_[d];
    v = v > 0.f ? v : SLOPE * v;
    eed[e] = v;
    atomicMax(&emax[d], ford(v));
}

__global__ void k_emax_fin(unsigned* __restrict__ em)
{
    int i = blockIdx.x*blockDim.x + threadIdx.x;
    if (i >= NTOT) return;
    float m = funord(em[i]);
    if (!isfinite(m)) m = 0.f;
    ((float*)em)[i] = m;
}

__global__ void k_edge2(const int* __restrict__ ei, float* __restrict__ eed,
                        const float* __restrict__ emaxf, float* __restrict__ den)
{
    int e = blockIdx.x*blockDim.x + threadIdx.x;
    if (e >= NEDGE) return;
    int d = ei[NEDGE + e];
    float num = expf(eed[e] - emaxf[d]);
    eed[e] = num;
    unsafeAtomicAdd(&den[d], num);
}

// out[dst] += alpha * h[src], 128 lanes per edge, 2 edges per block
__global__ void k_edge3(const int* __restrict__ ei, const float* __restrict__ num,
                        const float* __restrict__ den, const float* __restrict__ h,
                        float* __restrict__ outc)
{
    int tid = threadIdx.x;
    int le = tid >> 7;
    int j = tid & 127;
    int e = blockIdx.x*2 + le;
    if (e >= NEDGE) return;
    int s = ei[e], d = ei[NEDGE + e];
    float alpha = num[e] / fmaxf(den[d], 1e-16f);
    unsafeAtomicAdd(&outc[(long)d*D + j], alpha * h[(long)s*D + j]);
}

__global__ void k_finalize(const float* __restrict__ xC, const float* __restrict__ bias,
                           float* __restrict__ xA)
{
    long t = (long)blockIdx.x*blockDim.x + threadIdx.x;
    if (t >= (long)NTOT*D) return;
    xA[t] = celu_f(xC[t] + bias[t & (D-1)]);
}

// ---------------- post stage ----------------
__global__ void k_zero_deg(int* __restrict__ deg){ if (threadIdx.x < NPHENO) deg[threadIdx.x] = 0; }

__global__ void k_deg(const int* __restrict__ cts, int* __restrict__ deg)
{
    int c = blockIdx.x*blockDim.x + threadIdx.x;
    if (c < NCELLS) atomicAdd(&deg[cts[c]], 1);
}

__global__ void k_sample_pre(const float* __restrict__ zph, const int* __restrict__ deg,
                             const float* __restrict__ WP, const float* __restrict__ wgate,
                             float* __restrict__ preWP, float* __restrict__ pregate)
{
    __shared__ float hp[D];
    __shared__ float red[D];
    int s = blockIdx.x, j = threadIdx.x;
    float dn = sqrtf(fmaxf((float)deg[s], 1.f));
    float v = zph[s*D + j] / dn;
    hp[j] = v;
    __syncthreads();
    float acc = 0.f;
    for (int k = 0; k < D; ++k) acc = fmaf(hp[k], WP[k*D + j], acc);
    preWP[s*D + j] = acc;
    red[j] = v * wgate[D + j];
    __syncthreads();
    for (int st = 64; st; st >>= 1) { if (j < st) red[j] += red[j + st]; __syncthreads(); }
    if (j == 0) pregate[s] = red[0];
}

__global__ void k_cell_main(const float* __restrict__ xA, const int* __restrict__ cts,
                            const float* __restrict__ preWP, const float* __restrict__ pregate,
                            const float* __restrict__ wgate, const float* __restrict__ bgate,
                            float* __restrict__ out_x, float* __restrict__ g_out,
                            float* __restrict__ hinj)
{
    int lane = threadIdx.x & 63, wave = threadIdx.x >> 6;
    int wid = blockIdx.x*4 + wave;
    int nw = gridDim.x*4;
    float w0 = wgate[lane], w1 = wgate[64 + lane];
    float bg = bgate[0];
    for (int c = wid; c < NCELLS; c += nw) {
        const float* hr = xA + (long)(NGENES + c)*D;
        float h0 = hr[lane], h1 = hr[64 + lane];
        float part = wave_sum(h0*w0 + h1*w1);
        int s = cts[c];
        float gv = 1.f/(1.f + expf(-(part + pregate[s] + bg)));
        float hi0 = fmaf(gv, preWP[s*D + lane], h0);
        float hi1 = fmaf(gv, preWP[s*D + 64 + lane], h1);
        long orow = (long)(NGENES + c)*D;
        out_x[orow + lane] = hi0;
        out_x[orow + 64 + lane] = hi1;
        hinj[(long)c*D + lane] = hi0;
        hinj[(long)c*D + 64 + lane] = hi1;
        if (lane == 0) g_out[c] = gv;
    }
}

__global__ void k_copy_out(const float* __restrict__ xA, const float* __restrict__ zph,
                           float* __restrict__ out)
{
    int t = blockIdx.x*blockDim.x + threadIdx.x;
    if (t < NGENES*D) out[t] = xA[t];
    int u = t - NGENES*D;
    if (u >= 0 && u < NPHENO*D)
        out[(long)(NGENES + NCELLS)*D + u] = xA[(long)(NGENES + NCELLS)*D + u];
    int v = u - NPHENO*D;
    if (v >= 0 && v < NPHENO*D) out[O_ZPH + v] = zph[v];
}

extern "C" void kernel_launch(void* const* d_in, const int* in_sizes, int n_in,
                              void* d_out, int out_size, void* d_ws, size_t ws_size,
                              hipStream_t stream)
{
    const float* x       = (const float*)d_in[0];
    const int*   ei      = (const int*)  d_in[1];
    const float* praw    = (const float*)d_in[2];
    const int*   cts     = (const int*)  d_in[3];
    const float* Wg_gene = (const float*)d_in[4];
    const float* bg_gene = (const float*)d_in[5];
    const float* Wg_cell = (const float*)d_in[6];
    const float* bg_cell = (const float*)d_in[7];
    const float* c1W  = (const float*)d_in[8];
    const float* c1as = (const float*)d_in[9];
    const float* c1ad = (const float*)d_in[10];
    const float* c1b  = (const float*)d_in[11];
    const float* c2W  = (const float*)d_in[12];
    const float* c2as = (const float*)d_in[13];
    const float* c2ad = (const float*)d_in[14];
    const float* c2b  = (const float*)d_in[15];
    const float* mW1  = (const float*)d_in[16];
    const float* mb1  = (const float*)d_in[17];
    const float* mW2  = (const float*)d_in[18];
    const float* mb2  = (const float*)d_in[19];
    const float* WP   = (const float*)d_in[20];
    const float* wgate= (const float*)d_in[21];
    const float* bgate= (const float*)d_in[22];
    const float* Wsen = (const float*)d_in[23];
    const float* bsen = (const float*)d_in[24];
    const float* Wctx = (const float*)d_in[25];
    const float* bctx = (const float*)d_in[26];

    float* out = (float*)d_out;
    float* ws  = (float*)d_ws;
    float* xA   = ws;
    float* xB   = xA + (long)NTOT*D;
    float* xC   = xB + (long)NTOT*D;
    float* as_  = xC + (long)NTOT*D;
    float* ad_  = as_ + NTOT;
    float* emaxf= ad_ + NTOT;   unsigned* emaxu = (unsigned*)emaxf;
    float* den  = emaxf + NTOT;
    float* eed  = den + NTOT;              // NEDGE floats (e, then num in-place)
    float* zph  = eed + NEDGE;             // NPHENO*D
    float* preWP   = zph + NPHENO*D;       // NPHENO*D
    float* pregate = preWP + NPHENO*D;     // NPHENO
    int*   deg  = (int*)(pregate + NPHENO);

    dim3 B256(256);

    // node transforms + phenotype MLP -> xA (x_new)
    hipLaunchKernelGGL(k_pheno, dim3(NPHENO), dim3(D), 0, stream,
                       praw, mW1, mb1, mW2, mb2, zph, xA);
    hipLaunchKernelGGL((k_rowgemm<128,1,false>), dim3((NGENES+63)/64), B256, 0, stream,
                       x, Wg_gene, bg_gene, xA, nullptr, nullptr, nullptr, nullptr, NGENES);
    hipLaunchKernelGGL((k_rowgemm<128,1,false>), dim3((NCELLS+63)/64), B256, 0, stream,
                       x + (long)NGENES*D, Wg_cell, bg_cell, xA + (long)NGENES*D,
                       nullptr, nullptr, nullptr, nullptr, NCELLS);

    // two GAT layers
    for (int layer = 0; layer < 2; ++layer) {
        const float* W   = layer ? c2W  : c1W;
        const float* avs = layer ? c2as : c1as;
        const float* avd = layer ? c2ad : c1ad;
        const float* bb  = layer ? c2b  : c1b;
        hipLaunchKernelGGL((k_rowgemm<128,0,true>), dim3((NTOT+63)/64), B256, 0, stream,
                           xA, W, nullptr, xB, avs, avd, as_, ad_, NTOT);
        hipLaunchKernelGGL(k_init_layer, dim3((int)(((long)NTOT*D + 255)/256)), B256, 0, stream,
                           xC, emaxu, den);
        hipLaunchKernelGGL(k_edge1, dim3((NEDGE+255)/256), B256, 0, stream, ei, as_, ad_, eed, emaxu);
        hipLaunchKernelGGL(k_emax_fin, dim3((NTOT+255)/256), B256, 0, stream, emaxu);
        hipLaunchKernelGGL(k_edge2, dim3((NEDGE+255)/256), B256, 0, stream, ei, eed, emaxf, den);
        hipLaunchKernelGGL(k_edge3, dim3(NEDGE/2), B256, 0, stream, ei, eed, den, xB, xC);
        hipLaunchKernelGGL(k_finalize, dim3((int)(((long)NTOT*D + 255)/256)), B256, 0, stream,
                           xC, bb, xA);
    }

    // phenotype injection + heads
    hipLaunchKernelGGL(k_zero_deg, dim3(1), dim3(64), 0, stream, deg);
    hipLaunchKernelGGL(k_deg, dim3((NCELLS+255)/256), B256, 0, stream, cts, deg);
    hipLaunchKernelGGL(k_sample_pre, dim3(NPHENO), dim3(D), 0, stream,
                       zph, deg, WP, wgate, preWP, pregate);
    hipLaunchKernelGGL(k_cell_main, dim3(512), B256, 0, stream,
                       xA, cts, preWP, pregate, wgate, bgate,
                       out, out + O_G, xB);
    hipLaunchKernelGGL((k_rowgemm<128,2,false>), dim3((NCELLS+63)/64), B256, 0, stream,
                       xB, Wsen, bsen, out + O_ZSEN, nullptr, nullptr, nullptr, nullptr, NCELLS);
    hipLaunchKernelGGL((k_rowgemm<64,2,false>), dim3((NCELLS+63)/64), B256, 0, stream,
                       xB, Wctx, bctx, out + O_ZCTX, nullptr, nullptr, nullptr, nullptr, NCELLS);
    hipLaunchKernelGGL(k_copy_out, dim3((NGENES*D + 2*NPHENO*D + 255)/256), B256, 0, stream,
                       xA, zph, out);
}

// Round 2
// 1837.351 us; speedup vs baseline: 1.4913x; 1.4913x over previous
//
#include <hip/hip_runtime.h>
#include <math.h>

#define NGENES 2000
#define NCELLS 50000
#define NPHENO 64
#define NTOT   52064
#define NEDGE  1200000
#define D      128
#define SLOPE  0.2f

// output layout (flat, return order)
#define O_ZSEN 6664192LL                  // NTOT*D
#define O_ZCTX 13064192LL                 // + NCELLS*D
#define O_G    16264192LL                 // + NCELLS*64
#define O_ZPH  16314192LL                 // + NCELLS

__device__ __forceinline__ float celu_f(float x){ return x > 0.f ? x : expm1f(x); }
__device__ __forceinline__ float wave_sum(float v){
    #pragma unroll
    for (int off = 32; off; off >>= 1) v += __shfl_xor(v, off);
    return v;
}
__device__ __forceinline__ float wave_max(float v){
    #pragma unroll
    for (int off = 32; off; off >>= 1) v = fmaxf(v, __shfl_xor(v, off));
    return v;
}

// ---------------- dense row-GEMM: Y[r] = act(X[r] @ W + b), W in LDS ----------------
template<int NCOLS, int ACT, bool AVEC>
__launch_bounds__(256)
__global__ void k_rowgemm(const float* __restrict__ X, const float* __restrict__ W,
                          const float* __restrict__ bias, float* __restrict__ Y,
                          const float* __restrict__ avs, const float* __restrict__ avd,
                          float* __restrict__ as_out, float* __restrict__ ad_out,
                          int nrows)
{
    __shared__ float Wl[D*NCOLS];
    int tid = threadIdx.x;
    for (int k = tid; k < D*NCOLS; k += 256) Wl[k] = W[k];
    __syncthreads();
    const int lane = tid & 63, wave = tid >> 6;
    const int wid = blockIdx.x * 4 + wave;
    float b0 = 0.f, b1 = 0.f;
    if (bias) { b0 = bias[lane]; if (NCOLS == 128) b1 = bias[64 + lane]; }
    float s0=0.f, s1=0.f, dd0=0.f, dd1=0.f;
    if (AVEC) { s0 = avs[lane]; s1 = avs[64+lane]; dd0 = avd[lane]; dd1 = avd[64+lane]; }
    int r0 = wid * 16;
    int r1 = r0 + 16; if (r1 > nrows) r1 = nrows;
    for (int r = r0; r < r1; ++r) {
        float x0 = X[(long)r*D + lane];
        float x1 = X[(long)r*D + 64 + lane];
        float a0 = b0, a1 = b1;
        #pragma unroll
        for (int k = 0; k < 64; ++k) {
            float xk = __shfl(x0, k);
            a0 = fmaf(xk, Wl[k*NCOLS + lane], a0);
            if (NCOLS == 128) a1 = fmaf(xk, Wl[k*NCOLS + 64 + lane], a1);
        }
        #pragma unroll
        for (int k = 0; k < 64; ++k) {
            float xk = __shfl(x1, k);
            a0 = fmaf(xk, Wl[(64+k)*NCOLS + lane], a0);
            if (NCOLS == 128) a1 = fmaf(xk, Wl[(64+k)*NCOLS + 64 + lane], a1);
        }
        float o0 = a0, o1 = a1;
        if (ACT == 1) { o0 = fmaxf(o0, 0.f); o1 = fmaxf(o1, 0.f); }
        if (ACT == 2) { o0 = celu_f(o0); o1 = celu_f(o1); }
        Y[(long)r*NCOLS + lane] = o0;
        if (NCOLS == 128) Y[(long)r*NCOLS + 64 + lane] = o1;
        if (AVEC) {
            float ps = a0*s0 + a1*s1;
            float pd = a0*dd0 + a1*dd1;
            ps = wave_sum(ps); pd = wave_sum(pd);
            if (lane == 0) { as_out[r] = ps; ad_out[r] = pd; }
        }
    }
}

// ---------------- phenotype MLP ----------------
__global__ void k_pheno(const float* __restrict__ praw, const float* __restrict__ W1,
                        const float* __restrict__ b1, const float* __restrict__ W2,
                        const float* __restrict__ b2, float* __restrict__ zout,
                        float* __restrict__ xA)
{
    __shared__ float z1[D];
    int i = blockIdx.x, j = threadIdx.x;
    float p = praw[i];
    z1[j] = celu_f(fmaf(p, W1[j], b1[j]));
    __syncthreads();
    float acc = b2[j];
    for (int k = 0; k < D; ++k) acc = fmaf(z1[k], W2[k*D + j], acc);
    float z = celu_f(acc);
    zout[i*D + j] = z;
    xA[(long)(NGENES + NCELLS + i)*D + j] = z;
}

// ---------------- CSR build (once per call; reused by both layers) ----------------
__global__ void k_zero_i(int* __restrict__ p, int n)
{
    int i = blockIdx.x*blockDim.x + threadIdx.x;
    if (i < n) p[i] = 0;
}

__global__ void k_count(const int* __restrict__ ei, int* __restrict__ degn)
{
    int e = blockIdx.x*blockDim.x + threadIdx.x;
    if (e < NEDGE) atomicAdd(&degn[ei[NEDGE + e]], 1);
}

__launch_bounds__(1024)
__global__ void k_scan(const int* __restrict__ degn, int* __restrict__ off,
                       int* __restrict__ cursor)
{
    __shared__ int sums[1024];
    const int CH = (NTOT + 1023) / 1024;
    int t = threadIdx.x;
    int b = t*CH, e = b + CH; if (e > NTOT) e = NTOT; if (b > NTOT) b = NTOT;
    int s = 0;
    for (int i = b; i < e; ++i) s += degn[i];
    sums[t] = s;
    __syncthreads();
    for (int st = 1; st < 1024; st <<= 1) {
        int v = (t >= st) ? sums[t - st] : 0;
        __syncthreads();
        sums[t] += v;
        __syncthreads();
    }
    int pre = (t == 0) ? 0 : sums[t - 1];
    for (int i = b; i < e; ++i) { off[i] = pre; cursor[i] = pre; pre += degn[i]; }
    if (t == 1023) off[NTOT] = pre;
}

__global__ void k_scatter(const int* __restrict__ ei, int* __restrict__ cursor,
                          int* __restrict__ srcs)
{
    int e = blockIdx.x*blockDim.x + threadIdx.x;
    if (e >= NEDGE) return;
    int s = ei[e], d = ei[NEDGE + e];
    int pos = atomicAdd(&cursor[d], 1);
    srcs[pos] = s;
}

// ---------------- fused GAT layer: softmax-attention aggregate, one wave per dst ----------------
__launch_bounds__(256)
__global__ void k_gat(const int* __restrict__ off, const int* __restrict__ srcs,
                      const float* __restrict__ as_, const float* __restrict__ ad_,
                      const float* __restrict__ h, const float* __restrict__ bias,
                      float* __restrict__ outx)
{
    __shared__ float numb[4][64];
    __shared__ int   sb[4][64];
    const int lane = threadIdx.x & 63, wave = threadIdx.x >> 6;
    const int dst = blockIdx.x*4 + wave;
    if (dst >= NTOT) return;
    const int beg = off[dst], end = off[dst+1];
    const float adv = ad_[dst];

    // pass 1: segment max (as_ table is 208 KB, L1/L2-resident)
    float m = -INFINITY;
    for (int i = beg + lane; i < end; i += 64) {
        float v = as_[srcs[i]] + adv;
        v = v > 0.f ? v : SLOPE * v;
        m = fmaxf(m, v);
    }
    m = wave_max(m);

    // pass 2: exp weights + weighted gather-accumulate, 64-edge chunks
    float acc0 = 0.f, acc1 = 0.f, denp = 0.f;
    const float2* __restrict__ h2 = (const float2*)h;
    for (int base = beg; base < end; base += 64) {
        int n = end - base; if (n > 64) n = 64;
        float num = 0.f; int sidx = 0;
        if (lane < n) {
            sidx = srcs[base + lane];
            float v = as_[sidx] + adv;
            v = v > 0.f ? v : SLOPE * v;
            num = __expf(v - m);
        }
        denp += num;
        numb[wave][lane] = num;
        sb[wave][lane] = sidx;
        #pragma unroll 4
        for (int j = 0; j < n; ++j) {
            float nm = numb[wave][j];
            int s = sb[wave][j];
            float2 hv = h2[s*64 + lane];
            acc0 = fmaf(nm, hv.x, acc0);
            acc1 = fmaf(nm, hv.y, acc1);
        }
    }
    float den = wave_sum(denp);
    float inv = 1.f / fmaxf(den, 1e-16f);
    float2 bv = ((const float2*)bias)[lane];
    float o0 = celu_f(fmaf(acc0, inv, bv.x));
    float o1 = celu_f(fmaf(acc1, inv, bv.y));
    ((float2*)(outx + (long)dst*D))[lane] = make_float2(o0, o1);
}

// ---------------- post stage ----------------
__global__ void k_zero_deg(int* __restrict__ deg){ if (threadIdx.x < NPHENO) deg[threadIdx.x] = 0; }

__global__ void k_deg(const int* __restrict__ cts, int* __restrict__ deg)
{
    int c = blockIdx.x*blockDim.x + threadIdx.x;
    if (c < NCELLS) atomicAdd(&deg[cts[c]], 1);
}

__global__ void k_sample_pre(const float* __restrict__ zph, const int* __restrict__ deg,
                             const float* __restrict__ WP, const float* __restrict__ wgate,
                             float* __restrict__ preWP, float* __restrict__ pregate)
{
    __shared__ float hp[D];
    __shared__ float red[D];
    int s = blockIdx.x, j = threadIdx.x;
    float dn = sqrtf(fmaxf((float)deg[s], 1.f));
    float v = zph[s*D + j] / dn;
    hp[j] = v;
    __syncthreads();
    float acc = 0.f;
    for (int k = 0; k < D; ++k) acc = fmaf(hp[k], WP[k*D + j], acc);
    preWP[s*D + j] = acc;
    red[j] = v * wgate[D + j];
    __syncthreads();
    for (int st = 64; st; st >>= 1) { if (j < st) red[j] += red[j + st]; __syncthreads(); }
    if (j == 0) pregate[s] = red[0];
}

__global__ void k_cell_main(const float* __restrict__ xA, const int* __restrict__ cts,
                            const float* __restrict__ preWP, const float* __restrict__ pregate,
                            const float* __restrict__ wgate, const float* __restrict__ bgate,
                            float* __restrict__ out_x, float* __restrict__ g_out,
                            float* __restrict__ hinj)
{
    int lane = threadIdx.x & 63, wave = threadIdx.x >> 6;
    int wid = blockIdx.x*4 + wave;
    int nw = gridDim.x*4;
    float w0 = wgate[lane], w1 = wgate[64 + lane];
    float bg = bgate[0];
    for (int c = wid; c < NCELLS; c += nw) {
        const float* hr = xA + (long)(NGENES + c)*D;
        float h0 = hr[lane], h1 = hr[64 + lane];
        float part = wave_sum(h0*w0 + h1*w1);
        int s = cts[c];
        float gv = 1.f/(1.f + expf(-(part + pregate[s] + bg)));
        float hi0 = fmaf(gv, preWP[s*D + lane], h0);
        float hi1 = fmaf(gv, preWP[s*D + 64 + lane], h1);
        long orow = (long)(NGENES + c)*D;
        out_x[orow + lane] = hi0;
        out_x[orow + 64 + lane] = hi1;
        hinj[(long)c*D + lane] = hi0;
        hinj[(long)c*D + 64 + lane] = hi1;
        if (lane == 0) g_out[c] = gv;
    }
}

__global__ void k_copy_out(const float* __restrict__ xA, const float* __restrict__ zph,
                           float* __restrict__ out)
{
    int t = blockIdx.x*blockDim.x + threadIdx.x;
    if (t < NGENES*D) out[t] = xA[t];
    int u = t - NGENES*D;
    if (u >= 0 && u < NPHENO*D)
        out[(long)(NGENES + NCELLS)*D + u] = xA[(long)(NGENES + NCELLS)*D + u];
    int v = u - NPHENO*D;
    if (v >= 0 && v < NPHENO*D) out[O_ZPH + v] = zph[v];
}

extern "C" void kernel_launch(void* const* d_in, const int* in_sizes, int n_in,
                              void* d_out, int out_size, void* d_ws, size_t ws_size,
                              hipStream_t stream)
{
    const float* x       = (const float*)d_in[0];
    const int*   ei      = (const int*)  d_in[1];
    const float* praw    = (const float*)d_in[2];
    const int*   cts     = (const int*)  d_in[3];
    const float* Wg_gene = (const float*)d_in[4];
    const float* bg_gene = (const float*)d_in[5];
    const float* Wg_cell = (const float*)d_in[6];
    const float* bg_cell = (const float*)d_in[7];
    const float* c1W  = (const float*)d_in[8];
    const float* c1as = (const float*)d_in[9];
    const float* c1ad = (const float*)d_in[10];
    const float* c1b  = (const float*)d_in[11];
    const float* c2W  = (const float*)d_in[12];
    const float* c2as = (const float*)d_in[13];
    const float* c2ad = (const float*)d_in[14];
    const float* c2b  = (const float*)d_in[15];
    const float* mW1  = (const float*)d_in[16];
    const float* mb1  = (const float*)d_in[17];
    const float* mW2  = (const float*)d_in[18];
    const float* mb2  = (const float*)d_in[19];
    const float* WP   = (const float*)d_in[20];
    const float* wgate= (const float*)d_in[21];
    const float* bgate= (const float*)d_in[22];
    const float* Wsen = (const float*)d_in[23];
    const float* bsen = (const float*)d_in[24];
    const float* Wctx = (const float*)d_in[25];
    const float* bctx = (const float*)d_in[26];

    float* out = (float*)d_out;
    float* ws  = (float*)d_ws;
    float* xA   = ws;
    float* xB   = xA + (long)NTOT*D;
    float* as_  = xB + (long)NTOT*D;
    float* ad_  = as_ + NTOT;
    float* zph  = ad_ + NTOT;              // NPHENO*D
    float* preWP   = zph + NPHENO*D;       // NPHENO*D
    float* pregate = preWP + NPHENO*D;     // NPHENO
    int*   deg  = (int*)(pregate + NPHENO);        // NPHENO
    int*   degn = deg + NPHENO;                    // NTOT
    int*   off  = degn + NTOT;                     // NTOT+1
    int*   cursor = off + NTOT + 1;                // NTOT
    int*   srcs = cursor + NTOT + 1;               // NEDGE

    dim3 B256(256);

    // node transforms + phenotype MLP -> xA (x_new)
    hipLaunchKernelGGL(k_pheno, dim3(NPHENO), dim3(D), 0, stream,
                       praw, mW1, mb1, mW2, mb2, zph, xA);
    hipLaunchKernelGGL((k_rowgemm<128,1,false>), dim3((NGENES+63)/64), B256, 0, stream,
                       x, Wg_gene, bg_gene, xA, nullptr, nullptr, nullptr, nullptr, NGENES);
    hipLaunchKernelGGL((k_rowgemm<128,1,false>), dim3((NCELLS+63)/64), B256, 0, stream,
                       x + (long)NGENES*D, Wg_cell, bg_cell, xA + (long)NGENES*D,
                       nullptr, nullptr, nullptr, nullptr, NCELLS);

    // CSR build (dst-sorted edge list), reused by both layers
    hipLaunchKernelGGL(k_zero_i, dim3((NTOT+255)/256), B256, 0, stream, degn, NTOT);
    hipLaunchKernelGGL(k_count, dim3((NEDGE+255)/256), B256, 0, stream, ei, degn);
    hipLaunchKernelGGL(k_scan, dim3(1), dim3(1024), 0, stream, degn, off, cursor);
    hipLaunchKernelGGL(k_scatter, dim3((NEDGE+255)/256), B256, 0, stream, ei, cursor, srcs);

    // two GAT layers
    for (int layer = 0; layer < 2; ++layer) {
        const float* W   = layer ? c2W  : c1W;
        const float* avs = layer ? c2as : c1as;
        const float* avd = layer ? c2ad : c1ad;
        const float* bb  = layer ? c2b  : c1b;
        hipLaunchKernelGGL((k_rowgemm<128,0,true>), dim3((NTOT+63)/64), B256, 0, stream,
                           xA, W, nullptr, xB, avs, avd, as_, ad_, NTOT);
        hipLaunchKernelGGL(k_gat, dim3((NTOT+3)/4), B256, 0, stream,
                           off, srcs, as_, ad_, xB, bb, xA);
    }

    // phenotype injection + heads
    hipLaunchKernelGGL(k_zero_deg, dim3(1), dim3(64), 0, stream, deg);
    hipLaunchKernelGGL(k_deg, dim3((NCELLS+255)/256), B256, 0, stream, cts, deg);
    hipLaunchKernelGGL(k_sample_pre, dim3(NPHENO), dim3(D), 0, stream,
                       zph, deg, WP, wgate, preWP, pregate);
    hipLaunchKernelGGL(k_cell_main, dim3(512), B256, 0, stream,
                       xA, cts, preWP, pregate, wgate, bgate,
                       out, out + O_G, xB);
    hipLaunchKernelGGL((k_rowgemm<128,2,false>), dim3((NCELLS+63)/64), B256, 0, stream,
                       xB, Wsen, bsen, out + O_ZSEN, nullptr, nullptr, nullptr, nullptr, NCELLS);
    hipLaunchKernelGGL((k_rowgemm<64,2,false>), dim3((NCELLS+63)/64), B256, 0, stream,
                       xB, Wctx, bctx, out + O_ZCTX, nullptr, nullptr, nullptr, nullptr, NCELLS);
    hipLaunchKernelGGL(k_copy_out, dim3((NGENES*D + 2*NPHENO*D + 255)/256), B256, 0, stream,
                       xA, zph, out);
}